// Round 12
// baseline (244.394 us; speedup 1.0000x reference)
//
#include <hip/hip_runtime.h>
#include <math.h>

#define N_   128
#define S_   1024
#define D_   128
#define SD_  (S_ * D_)     // 131072

#define WSP_PLANE 49152    // 3*4*4*4*32*8  (one hi or lo W plane, elements)
#define NREP 16            // fallback (atomic) replica count
#define SB   2             // s-values per k_scores block
#define GRID_SC (S_ / SB)  // 512
#define QKP  36            // qk row pitch in shorts (72 B = 18 banks, conflict-free)

typedef __attribute__((ext_vector_type(8))) short bf16x8;
typedef __attribute__((ext_vector_type(4))) short bf16x4;
typedef __attribute__((ext_vector_type(4))) float f32x4;
#define MFMA16 __builtin_amdgcn_mfma_f32_16x16x32_bf16

// pe(s): row i = s>>5, col c = s&31; arg = pi*i*1000^(-(c&~1)/128); sin if c even
__device__ __forceinline__ float pe_scale(int s) {
    int i = s >> 5;
    int c = s & 31;
    double rexp = pow(1000.0, -(double)(c & ~1) / 128.0);
    double arg = M_PI * (double)i * rexp;
    return (float)((c & 1) ? cos(arg) : sin(arg));
}

__device__ __forceinline__ unsigned short bf16_rn(float f) {
    unsigned int u = __float_as_uint(f);
    u += 0x7fff + ((u >> 16) & 1);
    return (unsigned short)(u >> 16);
}
__device__ __forceinline__ float bf16_f(unsigned short h) {
    return __uint_as_float(((unsigned int)h) << 16);
}
__device__ __forceinline__ void split2(float f, unsigned short& h, unsigned short& l) {
    h = bf16_rn(f);
    l = bf16_rn(f - bf16_f(h));
}

// load 8 consecutive fp32, scale, split into hi/lo bf16x8 frags
__device__ __forceinline__ void load_split8(const float* p, float scale,
                                            bf16x8& hi, bf16x8& lo) {
    float4 u0 = *(const float4*)(p);
    float4 u1 = *(const float4*)(p + 4);
    unsigned short h[8], l[8];
    split2(u0.x * scale, h[0], l[0]); split2(u0.y * scale, h[1], l[1]);
    split2(u0.z * scale, h[2], l[2]); split2(u0.w * scale, h[3], l[3]);
    split2(u1.x * scale, h[4], l[4]); split2(u1.y * scale, h[5], l[5]);
    split2(u1.z * scale, h[6], l[6]); split2(u1.w * scale, h[7], l[7]);
    hi = bf16x8{(short)h[0],(short)h[1],(short)h[2],(short)h[3],
                (short)h[4],(short)h[5],(short)h[6],(short)h[7]};
    lo = bf16x8{(short)l[0],(short)l[1],(short)l[2],(short)l[3],
                (short)l[4],(short)l[5],(short)l[6],(short)l[7]};
}

// ---------------------------------------------------------------------------
// K0: split W (fp32 [384][128]) into hi/lo bf16 planes in MFMA-frag-swizzled
// layout Wsp[h][p][rc][ks][quad][m(32)][j(8)]. Also fills pe table (1024 f32).
// grid 192 x 256.
// ---------------------------------------------------------------------------
__global__ __launch_bounds__(256) void k_prep(const float* __restrict__ W,
                                              unsigned short* __restrict__ Wsp,
                                              float* __restrict__ peT) {
    const int idx = blockIdx.x * 256 + threadIdx.x;  // 0..49151
    if (idx < S_) peT[idx] = pe_scale(idx);
    const int rg = idx >> 7;         // W row (feature f)
    const int d  = idx & 127;
    const int p  = rg % 3;
    const int r  = rg / 3;
    const int rc = r >> 5, m = r & 31;
    const int ks = d >> 5, quad = (d >> 3) & 3, j = d & 7;
    unsigned short h, l;
    split2(W[idx], h, l);
    const size_t off = (size_t)((((p * 4 + rc) * 4 + ks) * 4 + quad) * 32 + m) * 8 + j;
    Wsp[off] = h;
    Wsp[off + WSP_PLANE] = l;
}

// ---------------------------------------------------------------------------
// K1: per-block partial scores over SB s-values via split-bf16 MFMA (R10
// structure: ping-pong qk, QKP=36, 8 barriers, 0 bank conflicts).
// NEW (fuse_v=1): also computes v_s = xs @ Wv^T (3-term split) using the
// SAME held xs frags (identical lane mapping as k_out's A-frags) and streams
// v to vws[s][r][n'] bf16 — k_out then only does PV. No new barriers; v-proj
// placed after the rc loop per ss (independent, non-LDS work).
// grid GRID_SC x 256.
// ---------------------------------------------------------------------------
__global__ __launch_bounds__(256, 2) void k_scores(const float* __restrict__ x,
                                                   const unsigned short* __restrict__ Wsp,
                                                   const float* __restrict__ b,
                                                   const float* __restrict__ peT,
                                                   float* __restrict__ sc,
                                                   unsigned short* __restrict__ vws,
                                                   int store_mode, int fuse_v) {
    __shared__ unsigned short qk[2][4][128 * QKP]; // [buf][qh,ql,kh,kl] : [n][r]
    __shared__ float bl[384];

    const int t    = threadIdx.x;
    const int lane = t & 63;
    const int wv   = t >> 6;        // wave 0..3
    const int lid  = lane & 15;
    const int quad = lane >> 4;

    if (t < 128) { bl[t] = b[t]; bl[t + 128] = b[t + 128]; bl[t + 256] = b[t + 256]; }
    __syncthreads();

    const f32x4 fzero = {0.f, 0.f, 0.f, 0.f};
    f32x4 sacc[2][8];
#pragma unroll
    for (int i = 0; i < 2; ++i)
#pragma unroll
        for (int j = 0; j < 8; ++j) sacc[i][j] = fzero;

    for (int ss = 0; ss < SB; ++ss) {
        const int s = blockIdx.x * SB + ss;
        const float ps = peT[s];

        // ---- held xs frags: rows n=(wv*2+nt)*16+lid, k=ks*32+quad*8 ----
        bf16x8 xh[2][4], xl[2][4];
#pragma unroll
        for (int nt = 0; nt < 2; ++nt) {
            const int row = (wv * 2 + nt) * 16 + lid;
            const float* xp = x + (size_t)row * SD_ + (size_t)s * D_;
#pragma unroll
            for (int ks = 0; ks < 4; ++ks)
                load_split8(xp + ks * 32 + quad * 8, ps, xh[nt][ks], xl[nt][ks]);
        }

        for (int rc = 0; rc < 4; ++rc) {
            const int buf = rc & 1;   // ping-pong
            // ---- projection: qT = Wp @ xs^T (3-term split), p=0:q 1:k ----
            for (int p = 0; p < 2; ++p) {
                f32x4 pacc[2][2];
                pacc[0][0] = fzero; pacc[0][1] = fzero;
                pacc[1][0] = fzero; pacc[1][1] = fzero;
#pragma unroll
                for (int ks = 0; ks < 4; ++ks) {
                    const unsigned short* wb =
                        Wsp + (size_t)(((p * 4 + rc) * 4 + ks) * 4 + quad) * 256;
                    bf16x8 wh[2], wl[2];
#pragma unroll
                    for (int mt = 0; mt < 2; ++mt) {
                        wh[mt] = *(const bf16x8*)(wb + (mt * 16 + lid) * 8);
                        wl[mt] = *(const bf16x8*)(wb + WSP_PLANE + (mt * 16 + lid) * 8);
                    }
#pragma unroll
                    for (int mt = 0; mt < 2; ++mt)
#pragma unroll
                        for (int nt = 0; nt < 2; ++nt) {
                            pacc[mt][nt] = MFMA16(wh[mt], xh[nt][ks], pacc[mt][nt], 0, 0, 0);
                            pacc[mt][nt] = MFMA16(wh[mt], xl[nt][ks], pacc[mt][nt], 0, 0, 0);
                            pacc[mt][nt] = MFMA16(wl[mt], xh[nt][ks], pacc[mt][nt], 0, 0, 0);
                        }
                }
                // epilogue: +bias, split, write transposed into qk[buf][..][n][r]
#pragma unroll
                for (int mt = 0; mt < 2; ++mt)
#pragma unroll
                    for (int nt = 0; nt < 2; ++nt) {
                        const int n = (wv * 2 + nt) * 16 + lid;
                        unsigned short hh[4], ll[4];
#pragma unroll
                        for (int r = 0; r < 4; ++r) {
                            const int rg = rc * 32 + mt * 16 + quad * 4 + r;
                            float qv = pacc[mt][nt][r] + bl[3 * rg + p];
                            split2(qv, hh[r], ll[r]);
                        }
                        bf16x4 hv = {(short)hh[0], (short)hh[1], (short)hh[2], (short)hh[3]};
                        bf16x4 lv = {(short)ll[0], (short)ll[1], (short)ll[2], (short)ll[3]};
                        *(bf16x4*)&qk[buf][p * 2 + 0][n * QKP + mt * 16 + quad * 4] = hv;
                        *(bf16x4*)&qk[buf][p * 2 + 1][n * QKP + mt * 16 + quad * 4] = lv;
                    }
            }
            __syncthreads();
            // ---- scores += q @ k^T over this 32-r chunk (3-term split) ----
            {
                bf16x8 qh[2], ql[2];
#pragma unroll
                for (int mt = 0; mt < 2; ++mt) {
                    const int row = wv * 32 + mt * 16 + lid;
                    qh[mt] = *(const bf16x8*)&qk[buf][0][row * QKP + quad * 8];
                    ql[mt] = *(const bf16x8*)&qk[buf][1][row * QKP + quad * 8];
                }
#pragma unroll
                for (int ntp = 0; ntp < 8; ++ntp) {
                    const int row = ntp * 16 + lid;
                    bf16x8 kh = *(const bf16x8*)&qk[buf][2][row * QKP + quad * 8];
                    bf16x8 kl = *(const bf16x8*)&qk[buf][3][row * QKP + quad * 8];
#pragma unroll
                    for (int mt = 0; mt < 2; ++mt) {
                        sacc[mt][ntp] = MFMA16(qh[mt], kh, sacc[mt][ntp], 0, 0, 0);
                        sacc[mt][ntp] = MFMA16(qh[mt], kl, sacc[mt][ntp], 0, 0, 0);
                        sacc[mt][ntp] = MFMA16(ql[mt], kh, sacc[mt][ntp], 0, 0, 0);
                    }
                }
            }
            // no trailing barrier (ping-pong ordering argument, see R10)
        }

        // ---- fused v-proj: v_s = xs @ Wv^T, streamed to vws[s][r][n'] ----
        if (fuse_v) {
            unsigned short* vs = vws + (size_t)s * (N_ * N_);
            for (int rc = 0; rc < 4; ++rc) {
                f32x4 vacc[2][2];
                vacc[0][0] = fzero; vacc[0][1] = fzero;
                vacc[1][0] = fzero; vacc[1][1] = fzero;
#pragma unroll
                for (int ks = 0; ks < 4; ++ks) {
                    const unsigned short* wb =
                        Wsp + (size_t)(((2 * 4 + rc) * 4 + ks) * 4 + quad) * 256;
                    bf16x8 wh[2], wl[2];
#pragma unroll
                    for (int wj = 0; wj < 2; ++wj) {
                        wh[wj] = *(const bf16x8*)(wb + (wj * 16 + lid) * 8);
                        wl[wj] = *(const bf16x8*)(wb + WSP_PLANE + (wj * 16 + lid) * 8);
                    }
#pragma unroll
                    for (int xi = 0; xi < 2; ++xi)
#pragma unroll
                        for (int wj = 0; wj < 2; ++wj) {
                            vacc[xi][wj] = MFMA16(xh[xi][ks], wh[wj], vacc[xi][wj], 0, 0, 0);
                            vacc[xi][wj] = MFMA16(xh[xi][ks], wl[wj], vacc[xi][wj], 0, 0, 0);
                            vacc[xi][wj] = MFMA16(xl[xi][ks], wh[wj], vacc[xi][wj], 0, 0, 0);
                        }
                }
#pragma unroll
                for (int xi = 0; xi < 2; ++xi)
#pragma unroll
                    for (int wj = 0; wj < 2; ++wj) {
                        const int r = rc * 32 + wj * 16 + lid;       // C col = W row
                        const int n = (wv * 2 + xi) * 16 + quad * 4; // C row = x row
                        const float bias = bl[3 * r + 2];
                        unsigned short hh[4];
#pragma unroll
                        for (int i = 0; i < 4; ++i)
                            hh[i] = bf16_rn(vacc[xi][wj][i] + bias);
                        bf16x4 hv = {(short)hh[0], (short)hh[1], (short)hh[2], (short)hh[3]};
                        *(bf16x4*)&vs[r * N_ + n] = hv;
                    }
            }
        }
    }

    // ---- write partial (store mode) or atomic accumulate (fallback) ----
    float* rep = sc + (store_mode ? (size_t)blockIdx.x * (N_ * N_)
                                  : (size_t)(blockIdx.x & (NREP - 1)) * (N_ * N_));
#pragma unroll
    for (int mt = 0; mt < 2; ++mt)
#pragma unroll
        for (int ntp = 0; ntp < 8; ++ntp)
#pragma unroll
            for (int r = 0; r < 4; ++r) {
                const int n  = wv * 32 + mt * 16 + quad * 4 + r;
                const int np = ntp * 16 + lid;
                if (store_mode) rep[n * N_ + np] = sacc[mt][ntp][r];
                else            atomicAdd(&rep[n * N_ + np], sacc[mt][ntp][r]);
            }
}

// ---------------------------------------------------------------------------
// K2: sum R partials/replicas, softmax, write attn pre-swizzled into B-frag
// layout att2[ks][quad][n][j]. grid 128 x 1024 threads (32-way replica split).
// ---------------------------------------------------------------------------
__global__ __launch_bounds__(1024) void k_softmax(const float* __restrict__ sc, int R,
                                                  unsigned short* __restrict__ att2) {
    const int n  = blockIdx.x;
    const int t  = threadIdx.x;          // 0..1023
    const int rg = t >> 5;               // 0..31: rep-group
    const int c4 = (t & 31) * 4;         // column quad

    float4 a = {0.f, 0.f, 0.f, 0.f};
    for (int rep = rg; rep < R; rep += 32) {
        const float4 p = *(const float4*)&sc[(size_t)rep * (N_ * N_) + n * N_ + c4];
        a.x += p.x; a.y += p.y; a.z += p.z; a.w += p.w;
    }
    __shared__ float tmp[32][128];
    *(float4*)&tmp[rg][c4] = a;
    __syncthreads();

    __shared__ float red[2];
    __shared__ float red2[2];

    float v = 0.f;
    if (t < 128) {
#pragma unroll
        for (int g = 0; g < 32; ++g) v += tmp[g][t];
        v *= 0.08838834764831845f;   // 1/sqrt(128)
    }

    float m = v;
#pragma unroll
    for (int o = 32; o > 0; o >>= 1) m = fmaxf(m, __shfl_xor(m, o));
    if (t < 128 && (t & 63) == 0) red[t >> 6] = m;
    __syncthreads();
    m = fmaxf(red[0], red[1]);

    float e = (t < 128) ? expf(v - m) : 0.f;
    float sum = e;
#pragma unroll
    for (int o = 32; o > 0; o >>= 1) sum += __shfl_xor(sum, o);
    if (t < 128 && (t & 63) == 0) red2[t >> 6] = sum;
    __syncthreads();
    sum = red2[0] + red2[1];

    if (t < 128) {
        const int ks = t >> 5, quad = (t >> 3) & 3, j = t & 7;
        att2[(size_t)(((ks * 4 + quad) * 128) + n) * 8 + j] = bf16_rn(e / sum);
    }
}

// ---------------------------------------------------------------------------
// K3: out[n, s*128+r] = sum_n' attn[n,n'] * v_s[n',r]. grid 1024 x 256.
// fuse_v=1: thin PV — v read from vws[s][r][n'] (computed in K1); no LDS
// for v, no x read, no Wv projection. fuse_v=0: legacy full body.
// ---------------------------------------------------------------------------
__global__ __launch_bounds__(256) void k_out(const float* __restrict__ x,
                                             const unsigned short* __restrict__ Wsp,
                                             const float* __restrict__ b,
                                             const unsigned short* __restrict__ att2,
                                             const float* __restrict__ peT,
                                             const unsigned short* __restrict__ vws,
                                             float* __restrict__ out,
                                             int fuse_v) {
    const int t    = threadIdx.x;
    const int lane = t & 63;
    const int wv   = t >> 6;
    const int lid  = lane & 15;
    const int quad = lane >> 4;
    const int s    = blockIdx.x;

    const f32x4 fzero = {0.f, 0.f, 0.f, 0.f};

    if (fuse_v) {
        // ---- thin PV: outT = v_s^T-frags @ attnT ----
        const unsigned short* vs = vws + (size_t)s * (N_ * N_);
        f32x4 oacc[2][8];
#pragma unroll
        for (int i = 0; i < 2; ++i)
#pragma unroll
            for (int j = 0; j < 8; ++j) oacc[i][j] = fzero;
#pragma unroll
        for (int ks = 0; ks < 4; ++ks) {
            const int kofs = ks * 32 + quad * 8;
            bf16x8 a[2];
#pragma unroll
            for (int mt = 0; mt < 2; ++mt)
                a[mt] = *(const bf16x8*)&vs[((wv * 2 + mt) * 16 + lid) * N_ + kofs];
#pragma unroll
            for (int nt = 0; nt < 8; ++nt) {
                bf16x8 bb = *(const bf16x8*)&att2[(size_t)(((ks * 4 + quad) * 128) +
                                                           (nt * 16 + lid)) * 8];
#pragma unroll
                for (int mt = 0; mt < 2; ++mt)
                    oacc[mt][nt] = MFMA16(a[mt], bb, oacc[mt][nt], 0, 0, 0);
            }
        }
#pragma unroll
        for (int mt = 0; mt < 2; ++mt)
#pragma unroll
            for (int nt = 0; nt < 8; ++nt) {
                const int r = (wv * 2 + mt) * 16 + quad * 4;
                const int n = nt * 16 + lid;
                *(float4*)&out[(size_t)n * SD_ + (size_t)s * D_ + r] = *(float4*)&oacc[mt][nt];
            }
        return;
    }

    // ================= legacy full body (fuse_v == 0) =================
    __shared__ unsigned short vT[128 * 136];     // [r][n'] bf16
    __shared__ float bv[128];
    const float ps = peT[s];

    if (t < 128) bv[t] = b[3 * t + 2];
    __syncthreads();

    bf16x8 xh[2][4], xl[2][4];
#pragma unroll
    for (int mt = 0; mt < 2; ++mt) {
        const int row = (wv * 2 + mt) * 16 + lid;
        const float* xp = x + (size_t)row * SD_ + (size_t)s * D_;
#pragma unroll
        for (int ks = 0; ks < 4; ++ks)
            load_split8(xp + ks * 32 + quad * 8, ps, xh[mt][ks], xl[mt][ks]);
    }

    for (int rc = 0; rc < 4; ++rc) {
        f32x4 vacc[2][2];
        vacc[0][0] = fzero; vacc[0][1] = fzero; vacc[1][0] = fzero; vacc[1][1] = fzero;
#pragma unroll
        for (int ks = 0; ks < 4; ++ks) {
            const unsigned short* wb =
                Wsp + (size_t)(((2 * 4 + rc) * 4 + ks) * 4 + quad) * 256;
            bf16x8 wh[2], wl[2];
#pragma unroll
            for (int nt = 0; nt < 2; ++nt) {
                wh[nt] = *(const bf16x8*)(wb + (nt * 16 + lid) * 8);
                wl[nt] = *(const bf16x8*)(wb + WSP_PLANE + (nt * 16 + lid) * 8);
            }
#pragma unroll
            for (int mt = 0; mt < 2; ++mt)
#pragma unroll
                for (int nt = 0; nt < 2; ++nt) {
                    vacc[mt][nt] = MFMA16(xh[mt][ks], wh[nt], vacc[mt][nt], 0, 0, 0);
                    vacc[mt][nt] = MFMA16(xh[mt][ks], wl[nt], vacc[mt][nt], 0, 0, 0);
                    vacc[mt][nt] = MFMA16(xl[mt][ks], wh[nt], vacc[mt][nt], 0, 0, 0);
                }
        }
#pragma unroll
        for (int mt = 0; mt < 2; ++mt)
#pragma unroll
            for (int nt = 0; nt < 2; ++nt) {
                const int r = rc * 32 + nt * 16 + lid;
                const float bias = bv[r];
                unsigned short hh[4];
#pragma unroll
                for (int i = 0; i < 4; ++i) hh[i] = bf16_rn(vacc[mt][nt][i] + bias);
                bf16x4 hv = {(short)hh[0], (short)hh[1], (short)hh[2], (short)hh[3]};
                *(bf16x4*)&vT[r * 136 + (wv * 2 + mt) * 16 + quad * 4] = hv;
            }
    }
    __syncthreads();

    {
        f32x4 oacc[2][8];
#pragma unroll
        for (int i = 0; i < 2; ++i)
#pragma unroll
            for (int j = 0; j < 8; ++j) oacc[i][j] = fzero;
#pragma unroll
        for (int ks = 0; ks < 4; ++ks) {
            const int kofs = ks * 32 + quad * 8;
            bf16x8 a[2];
#pragma unroll
            for (int mt = 0; mt < 2; ++mt)
                a[mt] = *(const bf16x8*)&vT[((wv * 2 + mt) * 16 + lid) * 136 + kofs];
#pragma unroll
            for (int nt = 0; nt < 8; ++nt) {
                bf16x8 bb = *(const bf16x8*)&att2[(size_t)(((ks * 4 + quad) * 128) +
                                                           (nt * 16 + lid)) * 8];
#pragma unroll
                for (int mt = 0; mt < 2; ++mt)
                    oacc[mt][nt] = MFMA16(a[mt], bb, oacc[mt][nt], 0, 0, 0);
            }
        }
#pragma unroll
        for (int mt = 0; mt < 2; ++mt)
#pragma unroll
            for (int nt = 0; nt < 8; ++nt) {
                const int r = (wv * 2 + mt) * 16 + quad * 4;
                const int n = nt * 16 + lid;
                *(float4*)&out[(size_t)n * SD_ + (size_t)s * D_ + r] = *(float4*)&oacc[mt][nt];
            }
    }
}

// ---------------------------------------------------------------------------
extern "C" void kernel_launch(void* const* d_in, const int* in_sizes, int n_in,
                              void* d_out, int out_size, void* d_ws, size_t ws_size,
                              hipStream_t stream) {
    const float* x = (const float*)d_in[0];
    const float* W = (const float*)d_in[1];
    const float* b = (const float*)d_in[2];
    float* out = (float*)d_out;

    const size_t store_bytes = (size_t)GRID_SC * N_ * N_ * sizeof(float);  // 32 MB
    const size_t rep_bytes   = (size_t)NREP * N_ * N_ * sizeof(float);     // 1 MB
    const size_t tail_bytes  = (size_t)N_ * N_ * sizeof(unsigned short)        // att2
                             + (size_t)2 * WSP_PLANE * sizeof(unsigned short)  // Wsp
                             + (size_t)S_ * sizeof(float);                     // peT
    const size_t vws_bytes   = (size_t)S_ * N_ * N_ * sizeof(unsigned short);  // 33.5 MB

    const int fuse_v     = (ws_size >= store_bytes + tail_bytes + vws_bytes) ? 1 : 0;
    const int store_mode = fuse_v ? 1
                         : (ws_size >= store_bytes + tail_bytes) ? 1 : 0;
    const size_t sc_bytes = store_mode ? store_bytes : rep_bytes;

    // ws layout: scores region | att2 32 KB | Wsp 192 KB | peT 4 KB | vws
    float* scores        = (float*)d_ws;
    unsigned short* att2 = (unsigned short*)((char*)d_ws + sc_bytes);
    unsigned short* Wsp  = att2 + N_ * N_;
    float* peT           = (float*)(Wsp + 2 * WSP_PLANE);
    unsigned short* vws  = (unsigned short*)(peT + S_);

    if (!store_mode)
        hipMemsetAsync(scores, 0, sc_bytes, stream);

    hipLaunchKernelGGL(k_prep,    dim3(192),     dim3(256),  0, stream, W, Wsp, peT);
    hipLaunchKernelGGL(k_scores,  dim3(GRID_SC), dim3(256),  0, stream, x, Wsp, b, peT,
                       scores, vws, store_mode, fuse_v);
    hipLaunchKernelGGL(k_softmax, dim3(N_),      dim3(1024), 0, stream, scores,
                       store_mode ? GRID_SC : NREP, att2);
    hipLaunchKernelGGL(k_out,     dim3(1024),    dim3(256),  0, stream, x, Wsp, b, att2,
                       peT, vws, out, fuse_v);
}

// Round 13
// 205.929 us; speedup vs baseline: 1.1868x; 1.1868x over previous
//
#include <hip/hip_runtime.h>
#include <math.h>

#define N_   128
#define S_   1024
#define D_   128
#define SD_  (S_ * D_)     // 131072

#define WSP_PLANE 49152    // 3*4*4*4*32*8  (one hi or lo W plane, elements)
#define NREP 16            // fallback (atomic) replica count
#define SB   2             // s-values per k_scores block
#define GRID_SC (S_ / SB)  // 512
#define QKP  36            // qk row pitch in shorts (72 B = 18 banks, conflict-free)

typedef __attribute__((ext_vector_type(8))) short bf16x8;
typedef __attribute__((ext_vector_type(4))) short bf16x4;
typedef __attribute__((ext_vector_type(4))) float f32x4;
#define MFMA16 __builtin_amdgcn_mfma_f32_16x16x32_bf16

// pe(s): row i = s>>5, col c = s&31; arg = pi*i*1000^(-(c&~1)/128); sin if c even
__device__ __forceinline__ float pe_scale(int s) {
    int i = s >> 5;
    int c = s & 31;
    double rexp = pow(1000.0, -(double)(c & ~1) / 128.0);
    double arg = M_PI * (double)i * rexp;
    return (float)((c & 1) ? cos(arg) : sin(arg));
}

__device__ __forceinline__ unsigned short bf16_rn(float f) {
    unsigned int u = __float_as_uint(f);
    u += 0x7fff + ((u >> 16) & 1);
    return (unsigned short)(u >> 16);
}
__device__ __forceinline__ float bf16_f(unsigned short h) {
    return __uint_as_float(((unsigned int)h) << 16);
}
__device__ __forceinline__ void split2(float f, unsigned short& h, unsigned short& l) {
    h = bf16_rn(f);
    l = bf16_rn(f - bf16_f(h));
}

// load 8 consecutive fp32, scale, split into hi/lo bf16x8 frags
__device__ __forceinline__ void load_split8(const float* p, float scale,
                                            bf16x8& hi, bf16x8& lo) {
    float4 u0 = *(const float4*)(p);
    float4 u1 = *(const float4*)(p + 4);
    unsigned short h[8], l[8];
    split2(u0.x * scale, h[0], l[0]); split2(u0.y * scale, h[1], l[1]);
    split2(u0.z * scale, h[2], l[2]); split2(u0.w * scale, h[3], l[3]);
    split2(u1.x * scale, h[4], l[4]); split2(u1.y * scale, h[5], l[5]);
    split2(u1.z * scale, h[6], l[6]); split2(u1.w * scale, h[7], l[7]);
    hi = bf16x8{(short)h[0],(short)h[1],(short)h[2],(short)h[3],
                (short)h[4],(short)h[5],(short)h[6],(short)h[7]};
    lo = bf16x8{(short)l[0],(short)l[1],(short)l[2],(short)l[3],
                (short)l[4],(short)l[5],(short)l[6],(short)l[7]};
}

// ---------------------------------------------------------------------------
// K0: split W (fp32 [384][128]) into hi/lo bf16 planes in MFMA-frag-swizzled
// layout Wsp[h][p][rc][ks][quad][m(32)][j(8)]. Also fills pe table (1024 f32).
// grid 192 x 256.
// ---------------------------------------------------------------------------
__global__ __launch_bounds__(256) void k_prep(const float* __restrict__ W,
                                              unsigned short* __restrict__ Wsp,
                                              float* __restrict__ peT) {
    const int idx = blockIdx.x * 256 + threadIdx.x;  // 0..49151
    if (idx < S_) peT[idx] = pe_scale(idx);
    const int rg = idx >> 7;         // W row (feature f)
    const int d  = idx & 127;
    const int p  = rg % 3;
    const int r  = rg / 3;
    const int rc = r >> 5, m = r & 31;
    const int ks = d >> 5, quad = (d >> 3) & 3, j = d & 7;
    unsigned short h, l;
    split2(W[idx], h, l);
    const size_t off = (size_t)((((p * 4 + rc) * 4 + ks) * 4 + quad) * 32 + m) * 8 + j;
    Wsp[off] = h;
    Wsp[off + WSP_PLANE] = l;
}

// ---------------------------------------------------------------------------
// K1: per-block partial scores over SB s-values via split-bf16 MFMA (R10
// structure: ping-pong qk, QKP=36, 8 barriers, 0 bank conflicts). The fused
// v-proj (R12) is REVERTED: it re-triggered the 128-arch-VGPR wall and
// spilled ~56 MB/dir scratch (FETCH 34->90, WRITE 33->122 MB).
// grid GRID_SC x 256.
// store_mode=1: write private 128x128 partial (no atomics, reduced in K2).
// ---------------------------------------------------------------------------
__global__ __launch_bounds__(256, 2) void k_scores(const float* __restrict__ x,
                                                   const unsigned short* __restrict__ Wsp,
                                                   const float* __restrict__ b,
                                                   const float* __restrict__ peT,
                                                   float* __restrict__ sc,
                                                   int store_mode) {
    __shared__ unsigned short qk[2][4][128 * QKP]; // [buf][qh,ql,kh,kl] : [n][r]
    __shared__ float bl[384];

    const int t    = threadIdx.x;
    const int lane = t & 63;
    const int wv   = t >> 6;        // wave 0..3
    const int lid  = lane & 15;
    const int quad = lane >> 4;

    if (t < 128) { bl[t] = b[t]; bl[t + 128] = b[t + 128]; bl[t + 256] = b[t + 256]; }
    __syncthreads();

    const f32x4 fzero = {0.f, 0.f, 0.f, 0.f};
    f32x4 sacc[2][8];
#pragma unroll
    for (int i = 0; i < 2; ++i)
#pragma unroll
        for (int j = 0; j < 8; ++j) sacc[i][j] = fzero;

    for (int ss = 0; ss < SB; ++ss) {
        const int s = blockIdx.x * SB + ss;
        const float ps = peT[s];

        // ---- held xs B-frags: rows n=(wv*2+nt)*16+lid, k=ks*32+quad*8 ----
        bf16x8 xh[2][4], xl[2][4];
#pragma unroll
        for (int nt = 0; nt < 2; ++nt) {
            const int row = (wv * 2 + nt) * 16 + lid;
            const float* xp = x + (size_t)row * SD_ + (size_t)s * D_;
#pragma unroll
            for (int ks = 0; ks < 4; ++ks)
                load_split8(xp + ks * 32 + quad * 8, ps, xh[nt][ks], xl[nt][ks]);
        }

        for (int rc = 0; rc < 4; ++rc) {
            const int buf = rc & 1;   // ping-pong
            // ---- projection: qT = Wp @ xs^T (3-term split), p=0:q 1:k ----
            for (int p = 0; p < 2; ++p) {
                f32x4 pacc[2][2];
                pacc[0][0] = fzero; pacc[0][1] = fzero;
                pacc[1][0] = fzero; pacc[1][1] = fzero;
#pragma unroll
                for (int ks = 0; ks < 4; ++ks) {
                    const unsigned short* wb =
                        Wsp + (size_t)(((p * 4 + rc) * 4 + ks) * 4 + quad) * 256;
                    bf16x8 wh[2], wl[2];
#pragma unroll
                    for (int mt = 0; mt < 2; ++mt) {
                        wh[mt] = *(const bf16x8*)(wb + (mt * 16 + lid) * 8);
                        wl[mt] = *(const bf16x8*)(wb + WSP_PLANE + (mt * 16 + lid) * 8);
                    }
#pragma unroll
                    for (int mt = 0; mt < 2; ++mt)
#pragma unroll
                        for (int nt = 0; nt < 2; ++nt) {
                            pacc[mt][nt] = MFMA16(wh[mt], xh[nt][ks], pacc[mt][nt], 0, 0, 0);
                            pacc[mt][nt] = MFMA16(wh[mt], xl[nt][ks], pacc[mt][nt], 0, 0, 0);
                            pacc[mt][nt] = MFMA16(wl[mt], xh[nt][ks], pacc[mt][nt], 0, 0, 0);
                        }
                }
                // epilogue: +bias, split, write transposed into qk[buf][..][n][r]
#pragma unroll
                for (int mt = 0; mt < 2; ++mt)
#pragma unroll
                    for (int nt = 0; nt < 2; ++nt) {
                        const int n = (wv * 2 + nt) * 16 + lid;
                        unsigned short hh[4], ll[4];
#pragma unroll
                        for (int r = 0; r < 4; ++r) {
                            const int rg = rc * 32 + mt * 16 + quad * 4 + r;
                            float qv = pacc[mt][nt][r] + bl[3 * rg + p];
                            split2(qv, hh[r], ll[r]);
                        }
                        bf16x4 hv = {(short)hh[0], (short)hh[1], (short)hh[2], (short)hh[3]};
                        bf16x4 lv = {(short)ll[0], (short)ll[1], (short)ll[2], (short)ll[3]};
                        *(bf16x4*)&qk[buf][p * 2 + 0][n * QKP + mt * 16 + quad * 4] = hv;
                        *(bf16x4*)&qk[buf][p * 2 + 1][n * QKP + mt * 16 + quad * 4] = lv;
                    }
            }
            __syncthreads();
            // ---- scores += q @ k^T over this 32-r chunk (3-term split) ----
            {
                bf16x8 qh[2], ql[2];
#pragma unroll
                for (int mt = 0; mt < 2; ++mt) {
                    const int row = wv * 32 + mt * 16 + lid;
                    qh[mt] = *(const bf16x8*)&qk[buf][0][row * QKP + quad * 8];
                    ql[mt] = *(const bf16x8*)&qk[buf][1][row * QKP + quad * 8];
                }
#pragma unroll
                for (int ntp = 0; ntp < 8; ++ntp) {
                    const int row = ntp * 16 + lid;
                    bf16x8 kh = *(const bf16x8*)&qk[buf][2][row * QKP + quad * 8];
                    bf16x8 kl = *(const bf16x8*)&qk[buf][3][row * QKP + quad * 8];
#pragma unroll
                    for (int mt = 0; mt < 2; ++mt) {
                        sacc[mt][ntp] = MFMA16(qh[mt], kh, sacc[mt][ntp], 0, 0, 0);
                        sacc[mt][ntp] = MFMA16(qh[mt], kl, sacc[mt][ntp], 0, 0, 0);
                        sacc[mt][ntp] = MFMA16(ql[mt], kh, sacc[mt][ntp], 0, 0, 0);
                    }
                }
            }
            // no trailing barrier: next rc writes the OTHER buffer; reuse of
            // this buffer (rc+2) is ordered by the rc+1 barrier.
        }
    }

    // ---- write partial (store mode) or atomic accumulate (fallback) ----
    float* rep = sc + (store_mode ? (size_t)blockIdx.x * (N_ * N_)
                                  : (size_t)(blockIdx.x & (NREP - 1)) * (N_ * N_));
#pragma unroll
    for (int mt = 0; mt < 2; ++mt)
#pragma unroll
        for (int ntp = 0; ntp < 8; ++ntp)
#pragma unroll
            for (int r = 0; r < 4; ++r) {
                const int n  = wv * 32 + mt * 16 + quad * 4 + r;
                const int np = ntp * 16 + lid;
                if (store_mode) rep[n * N_ + np] = sacc[mt][ntp][r];
                else            atomicAdd(&rep[n * N_ + np], sacc[mt][ntp][r]);
            }
}

// ---------------------------------------------------------------------------
// K2: sum R partials/replicas, softmax, write attn pre-swizzled into B-frag
// layout att2[ks][quad][n][j]. grid 128 x 1024 threads (32-way replica split).
// ---------------------------------------------------------------------------
__global__ __launch_bounds__(1024) void k_softmax(const float* __restrict__ sc, int R,
                                                  unsigned short* __restrict__ att2) {
    const int n  = blockIdx.x;
    const int t  = threadIdx.x;          // 0..1023
    const int rg = t >> 5;               // 0..31: rep-group
    const int c4 = (t & 31) * 4;         // column quad

    float4 a = {0.f, 0.f, 0.f, 0.f};
    for (int rep = rg; rep < R; rep += 32) {
        const float4 p = *(const float4*)&sc[(size_t)rep * (N_ * N_) + n * N_ + c4];
        a.x += p.x; a.y += p.y; a.z += p.z; a.w += p.w;
    }
    __shared__ float tmp[32][128];
    *(float4*)&tmp[rg][c4] = a;
    __syncthreads();

    __shared__ float red[2];
    __shared__ float red2[2];

    float v = 0.f;
    if (t < 128) {
#pragma unroll
        for (int g = 0; g < 32; ++g) v += tmp[g][t];
        v *= 0.08838834764831845f;   // 1/sqrt(128)
    }

    float m = v;
#pragma unroll
    for (int o = 32; o > 0; o >>= 1) m = fmaxf(m, __shfl_xor(m, o));
    if (t < 128 && (t & 63) == 0) red[t >> 6] = m;
    __syncthreads();
    m = fmaxf(red[0], red[1]);

    float e = (t < 128) ? expf(v - m) : 0.f;
    float sum = e;
#pragma unroll
    for (int o = 32; o > 0; o >>= 1) sum += __shfl_xor(sum, o);
    if (t < 128 && (t & 63) == 0) red2[t >> 6] = sum;
    __syncthreads();
    sum = red2[0] + red2[1];

    if (t < 128) {
        const int ks = t >> 5, quad = (t >> 3) & 3, j = t & 7;
        att2[(size_t)(((ks * 4 + quad) * 128) + n) * 8 + j] = bf16_rn(e / sum);
    }
}

// ---------------------------------------------------------------------------
// K3: out[n, s*128+r] = sum_n' attn[n,n'] * v_s[n',r]. grid 1024 x 256.
// LDS: vT only (~35KB). Wv from pre-split Wsp (p=2), attn from att2.
// PV uses SWAPPED MFMA operands (attn as A, v as B) so the C layout puts r
// on lid (contiguous across lanes) -> each scalar store instruction writes
// 4 rows x 64B packed segments instead of 64 lanes x 16B at 512KB stride.
// ---------------------------------------------------------------------------
__global__ __launch_bounds__(256, 2) void k_out(const float* __restrict__ x,
                                                const unsigned short* __restrict__ Wsp,
                                                const float* __restrict__ b,
                                                const unsigned short* __restrict__ att2,
                                                const float* __restrict__ peT,
                                                float* __restrict__ out) {
    __shared__ unsigned short vT[128 * 136];     // [r][n'] bf16
    __shared__ float bv[128];

    const int t    = threadIdx.x;
    const int lane = t & 63;
    const int wv   = t >> 6;
    const int lid  = lane & 15;
    const int quad = lane >> 4;
    const int s    = blockIdx.x;
    const float ps = peT[s];

    if (t < 128) bv[t] = b[3 * t + 2];
    __syncthreads();

    const f32x4 fzero = {0.f, 0.f, 0.f, 0.f};

    // ---- held xs A-frags: rows n=(wv*2+mt)*16+lid ----
    bf16x8 xh[2][4], xl[2][4];
#pragma unroll
    for (int mt = 0; mt < 2; ++mt) {
        const int row = (wv * 2 + mt) * 16 + lid;
        const float* xp = x + (size_t)row * SD_ + (size_t)s * D_;
#pragma unroll
        for (int ks = 0; ks < 4; ++ks)
            load_split8(xp + ks * 32 + quad * 8, ps, xh[mt][ks], xl[mt][ks]);
    }

    // ---- v-proj: v = xs @ Wv^T (3-term split); vT chunks disjoint, no syncs ----
    for (int rc = 0; rc < 4; ++rc) {
        f32x4 vacc[2][2];
        vacc[0][0] = fzero; vacc[0][1] = fzero; vacc[1][0] = fzero; vacc[1][1] = fzero;
#pragma unroll
        for (int ks = 0; ks < 4; ++ks) {
            const unsigned short* wb =
                Wsp + (size_t)(((2 * 4 + rc) * 4 + ks) * 4 + quad) * 256;
            bf16x8 wh[2], wl[2];
#pragma unroll
            for (int nt = 0; nt < 2; ++nt) {
                wh[nt] = *(const bf16x8*)(wb + (nt * 16 + lid) * 8);
                wl[nt] = *(const bf16x8*)(wb + WSP_PLANE + (nt * 16 + lid) * 8);
            }
#pragma unroll
            for (int mt = 0; mt < 2; ++mt)
#pragma unroll
                for (int nt = 0; nt < 2; ++nt) {
                    vacc[mt][nt] = MFMA16(xh[mt][ks], wh[nt], vacc[mt][nt], 0, 0, 0);
                    vacc[mt][nt] = MFMA16(xh[mt][ks], wl[nt], vacc[mt][nt], 0, 0, 0);
                    vacc[mt][nt] = MFMA16(xl[mt][ks], wh[nt], vacc[mt][nt], 0, 0, 0);
                }
        }
#pragma unroll
        for (int mt = 0; mt < 2; ++mt)
#pragma unroll
            for (int nt = 0; nt < 2; ++nt) {
                const int r = rc * 32 + nt * 16 + lid;
                const float bias = bv[r];
                unsigned short hh[4];
#pragma unroll
                for (int i = 0; i < 4; ++i) hh[i] = bf16_rn(vacc[mt][nt][i] + bias);
                bf16x4 hv = {(short)hh[0], (short)hh[1], (short)hh[2], (short)hh[3]};
                *(bf16x4*)&vT[r * 136 + (wv * 2 + mt) * 16 + quad * 4] = hv;
            }
    }
    __syncthreads();

    // ---- PV (swapped): C = attn(A) @ v(B): row(M)=n, col(N)=r ----
    {
        f32x4 oacc[2][8];
#pragma unroll
        for (int i = 0; i < 2; ++i)
#pragma unroll
            for (int j = 0; j < 8; ++j) oacc[i][j] = fzero;
#pragma unroll
        for (int ks = 0; ks < 4; ++ks) {
            const int kofs = ks * 32 + quad * 8;
            bf16x8 a[2];
#pragma unroll
            for (int mt = 0; mt < 2; ++mt)
                a[mt] = *(const bf16x8*)&vT[((wv * 2 + mt) * 16 + lid) * 136 + kofs];
#pragma unroll
            for (int nt = 0; nt < 8; ++nt) {
                bf16x8 bb = *(const bf16x8*)&att2[(size_t)(((ks * 4 + quad) * 128) +
                                                           (nt * 16 + lid)) * 8];
#pragma unroll
                for (int mt = 0; mt < 2; ++mt)
                    oacc[mt][nt] = MFMA16(bb, a[mt], oacc[mt][nt], 0, 0, 0);
            }
        }
        // stores: n = nt*16 + quad*4 + reg (row), r = (wv*2+mt)*16 + lid (col);
        // lanes sweep r contiguously -> 4 x 64B packed segments per instr.
#pragma unroll
        for (int mt = 0; mt < 2; ++mt) {
            const int r = (wv * 2 + mt) * 16 + lid;
#pragma unroll
            for (int nt = 0; nt < 8; ++nt)
#pragma unroll
                for (int reg = 0; reg < 4; ++reg) {
                    const int n = nt * 16 + quad * 4 + reg;
                    out[(size_t)n * SD_ + (size_t)s * D_ + r] = oacc[mt][nt][reg];
                }
        }
    }
}

// ---------------------------------------------------------------------------
extern "C" void kernel_launch(void* const* d_in, const int* in_sizes, int n_in,
                              void* d_out, int out_size, void* d_ws, size_t ws_size,
                              hipStream_t stream) {
    const float* x = (const float*)d_in[0];
    const float* W = (const float*)d_in[1];
    const float* b = (const float*)d_in[2];
    float* out = (float*)d_out;

    const size_t store_bytes = (size_t)GRID_SC * N_ * N_ * sizeof(float);  // 32 MB
    const size_t rep_bytes   = (size_t)NREP * N_ * N_ * sizeof(float);     // 1 MB
    const size_t tail_bytes  = (size_t)N_ * N_ * sizeof(unsigned short)        // att2
                             + (size_t)2 * WSP_PLANE * sizeof(unsigned short)  // Wsp
                             + (size_t)S_ * sizeof(float);                     // peT
    const int store_mode = (ws_size >= store_bytes + tail_bytes) ? 1 : 0;
    const size_t sc_bytes = store_mode ? store_bytes : rep_bytes;

    // ws layout: scores region | att2 32 KB | Wsp 192 KB | peT 4 KB
    float* scores        = (float*)d_ws;
    unsigned short* att2 = (unsigned short*)((char*)d_ws + sc_bytes);
    unsigned short* Wsp  = att2 + N_ * N_;
    float* peT           = (float*)(Wsp + 2 * WSP_PLANE);

    if (!store_mode)
        hipMemsetAsync(scores, 0, sc_bytes, stream);

    hipLaunchKernelGGL(k_prep,    dim3(192),     dim3(256),  0, stream, W, Wsp, peT);
    hipLaunchKernelGGL(k_scores,  dim3(GRID_SC), dim3(256),  0, stream, x, Wsp, b, peT,
                       scores, store_mode);
    hipLaunchKernelGGL(k_softmax, dim3(N_),      dim3(1024), 0, stream, scores,
                       store_mode ? GRID_SC : NREP, att2);
    hipLaunchKernelGGL(k_out,     dim3(1024),    dim3(256),  0, stream, x, Wsp, b, att2,
                       peT, out);
}